// Round 14
// baseline (105.261 us; speedup 1.0000x reference)
//
#include <hip/hip_runtime.h>

#define EPSF 1e-10f
#define KPN 32
#define HH 96
#define WW 96
#define NPIX (HH*WW)     // 9216
#define CH 3
#define SH 128
#define SW 128
#define NIMG 64

__device__ inline float wred_sum(float v){
  #pragma unroll
  for(int off=32; off; off>>=1) v += __shfl_xor(v, off, 64);
  return v;
}
__device__ inline float wred_max(float v){
  #pragma unroll
  for(int off=32; off; off>>=1) v = fmaxf(v, __shfl_xor(v, off, 64));
  return v;
}

// ---------------- resize: jax.image.resize bilinear, antialias=True, 128->96 ----------------
__global__ __launch_bounds__(256) void k_resize(const float* __restrict__ img, float* __restrict__ out){
  int idx = blockIdx.x*256 + threadIdx.x;
  if (idx >= NIMG*CH*NPIX) return;
  int ox = idx % WW;
  int oy = (idx / WW) % HH;
  int nc = idx / NPIX;
  float xs = (ox + 0.5f)*(4.0f/3.0f) - 0.5f;
  float ys = (oy + 0.5f)*(4.0f/3.0f) - 0.5f;
  int jx0 = (int)ceilf(xs - 4.0f/3.0f);
  int jy0 = (int)ceilf(ys - 4.0f/3.0f);
  float wx[3], wy[3]; float sx=0.f, sy=0.f;
  #pragma unroll
  for(int t=0;t<3;t++){
    int j = jx0+t;
    float w = 1.0f - 0.75f*fabsf((float)j - xs);
    w = (j>=0 && j<SW) ? fmaxf(w,0.0f) : 0.0f;
    wx[t]=w; sx+=w;
    j = jy0+t;
    w = 1.0f - 0.75f*fabsf((float)j - ys);
    w = (j>=0 && j<SH) ? fmaxf(w,0.0f) : 0.0f;
    wy[t]=w; sy+=w;
  }
  float inv = 1.0f/(sx*sy);
  const float* base = img + (size_t)nc*SH*SW;
  float acc=0.f;
  #pragma unroll
  for(int ty=0;ty<3;ty++){
    if (wy[ty]==0.f) continue;
    int jy = min(max(jy0+ty,0), SH-1);
    #pragma unroll
    for(int tx=0;tx<3;tx++){
      if (wx[tx]==0.f) continue;
      int jx = min(max(jx0+tx,0), SW-1);
      acc += wy[ty]*wx[tx]*base[jy*SW+jx];
    }
  }
  out[idx] = acc*inv;
}

// ---------------- local entropy ----------------
// R8 structure (channel-split, 2x2 outputs, 4x4 reg halo, direct per-bin
// exps) with k-row STREAMED into column-sums: no k[4][4] materialization,
// live state {v[16], vs[8], S/T[8]} ~34 floats -> VGPR target <=84 ->
// 6 waves/SIMD (R8 sat at 128 -> 4/SIMD, VALUBusy 37%).
// (R13's shfl variant made the RA pick VGPR=28 and spill 21 MB - reverted.)
// OOB sentinel v=1e4 underflows exp to +0.
__global__ __launch_bounds__(256) void k_entropy(const float* __restrict__ rimg, float* __restrict__ ent){
  int tid = threadIdx.x;
  int n = blockIdx.y;
  int ch = blockIdx.z;
  int idx = blockIdx.x*256 + tid;    // 0..2303
  int rg = idx / 48, cg = idx % 48;
  int r0 = rg*2, c0 = cg*2;
  const float* src = rimg + ((size_t)(n*CH+ch))*NPIX;
  float v[4][4];
  #pragma unroll
  for (int r=0;r<4;r++){
    int gr = r0-1+r;
    bool rok = (gr>=0 && gr<HH);
    #pragma unroll
    for (int c=0;c<4;c++){
      int gc = c0-1+c;
      v[r][c] = (rok && gc>=0 && gc<WW) ? src[gr*96+gc] : 1e4f;
    }
  }
  float S[2][2]={{0.f,0.f},{0.f,0.f}}, T[2][2]={{0.f,0.f},{0.f,0.f}};
  #pragma unroll 4
  for (int b=0;b<16;b++){
    float cb = (float)b * (1.0f/15.0f);
    float vs[2][4] = {{0.f,0.f,0.f,0.f},{0.f,0.f,0.f,0.f}};
    #pragma unroll
    for (int r=0;r<4;r++)
      #pragma unroll
      for (int c=0;c<4;c++){
        float d = v[r][c] - cb;
        float k = __expf(-50.f*d*d);
        if (r<=2) vs[0][c] += k;   // window rows 0..2
        if (r>=1) vs[1][c] += k;   // window rows 1..3
      }
    #pragma unroll
    for (int rr=0;rr<2;rr++)
      #pragma unroll
      for (int cc=0;cc<2;cc++){
        float p = (vs[rr][cc]+vs[rr][cc+1]+vs[rr][cc+2])*(1.f/9.f);
        S[rr][cc] += p;
        T[rr][cc] += p*__logf(p+EPSF);
      }
  }
  #pragma unroll
  for (int rr=0;rr<2;rr++)
    #pragma unroll
    for (int cc=0;cc<2;cc++){
      float Sp = S[rr][cc]+EPSF;
      float e = (__logf(Sp) - T[rr][cc]/Sp)*(1.f/3.f);
      atomicAdd(&ent[(size_t)n*NPIX + (size_t)(r0+rr)*96 + (c0+cc)], e);
    }
}

// ---------------- main gaussians pass ----------------
// s-split + R12 asm pipeline (depth-16 volatile loads, counted vmcnt) +
// R13 XCD-aware block remap (wgid%8 == n>>3: consecutive-n blocks colocate
// per XCD so the prev-s plane reuse L2-hits). R13: 56 -> ~21 us.
__global__ __launch_bounds__(256, 4) void k_main(const float* __restrict__ gauss,
                                              const float* __restrict__ status,
                                              const float* __restrict__ ent,
                                              float* __restrict__ miS,
                                              float* __restrict__ melN,
                                              float* __restrict__ mcelN,
                                              float* __restrict__ reS,
                                              float* __restrict__ ceS,
                                              unsigned int* __restrict__ gmax,
                                              float* __restrict__ hsG){
  __shared__ float stc[32], stq[32];
  int tid = threadIdx.x;
  int lane = tid & 63;
  int wgid = blockIdx.x;          // 0..1151
  int xcd = wgid & 7;
  int q_ = wgid >> 3;             // 0..143
  int tile = q_ % 18;             // 0..17
  int n = xcd*8 + q_/18;          // 0..63
  int s = n & 3;
  int np = (s==0) ? n+3 : n-1;
  bool nz = (n==0);
  if (tid < 32) stc[tid] = status[n*32 + tid];
  else if (tid < 64) stq[tid-32] = status[np*32 + (tid-32)];
  __syncthreads();
  unsigned off = (unsigned)(tile*256 + tid);     // float2 index within a plane
  const float2* __restrict__ gc = (const float2*)gauss + (size_t)n*32*4608 + off;
  const float2* __restrict__ gq = (const float2*)gauss + (size_t)np*32*4608 + off;
  const float2* __restrict__ e2 = (const float2*)ent;
  float2 re2 = e2[(size_t)n*4608 + off];
  float2 se2 = e2[(size_t)np*4608 + off];
  float cex = fmaxf(re2.x, se2.x) - se2.x;   // relu(re-se)
  float cey = fmaxf(re2.y, se2.y) - se2.y;
  float Kx  = fmaxf(se2.x - re2.x, 0.f);     // relu(se-re)
  float Ky  = fmaxf(se2.y - re2.y, 0.f);
  float amx=0.f, amy=0.f, agx=0.f, agy=0.f, mix=0.f, miy=0.f;
  float hsacc = 0.f;
  float2 G[8], H[8];

#define GLD(dst, addr) asm volatile("global_load_dwordx2 %0, %1, off" : "=v"(dst) : "v"(addr) : "memory")
#define VMWAIT(N) asm volatile("s_waitcnt vmcnt(" #N ")" ::: "memory")

#define PROC(g, h, KP) { \
  float sc = stc[KP], sp = stq[KP]; \
  float hmx = fminf(fmaxf(__builtin_fmaf((g).x, 3.5f, -0.35f), 0.f), 1.f); \
  float hmy = fminf(fmaxf(__builtin_fmaf((g).y, 3.5f, -0.35f), 0.f), 1.f); \
  float hpx = fminf(fmaxf(__builtin_fmaf((h).x, 3.5f, -0.35f), 0.f), 1.f); \
  float hpy = fminf(fmaxf(__builtin_fmaf((h).y, 3.5f, -0.35f), 0.f), 1.f); \
  if (nz && (KP)==0) hsacc = hmx + hmy; \
  float ahx = sc*hmx, ahy = sc*hmy; \
  float shx = sp*hpx, shy = sp*hpy; \
  amx += ahx; amy += ahy; \
  agx += (g).x; agy += (g).y; \
  float Dx = __builtin_fmaf(-se2.x, shx, Kx); \
  float Dy = __builtin_fmaf(-se2.y, shy, Ky); \
  mix += fminf((1.f - ahx)*Dx, 0.f); \
  miy += fminf((1.f - ahy)*Dy, 0.f); }

#define STEP(I, WN) { \
  VMWAIT(WN); \
  __builtin_amdgcn_sched_barrier(0); \
  PROC(G[(I)&7], H[(I)&7], (I)); \
  if ((I) < 24){ GLD(G[(I)&7], gc + ((I)+8)*4608); GLD(H[(I)&7], gq + ((I)+8)*4608); } \
}

  __builtin_amdgcn_sched_barrier(0);
  #pragma unroll
  for (int j=0;j<8;j++){ GLD(G[j], gc + j*4608); GLD(H[j], gq + j*4608); }

  STEP(0,14)  STEP(1,14)  STEP(2,14)  STEP(3,14)
  STEP(4,14)  STEP(5,14)  STEP(6,14)  STEP(7,14)
  STEP(8,14)  STEP(9,14)  STEP(10,14) STEP(11,14)
  STEP(12,14) STEP(13,14) STEP(14,14) STEP(15,14)
  STEP(16,14) STEP(17,14) STEP(18,14) STEP(19,14)
  STEP(20,14) STEP(21,14) STEP(22,14) STEP(23,14)
  STEP(24,14) STEP(25,12) STEP(26,10) STEP(27,8)
  STEP(28,6)  STEP(29,4)  STEP(30,2)  STEP(31,0)

#undef STEP
#undef PROC
#undef VMWAIT
#undef GLD

  float qx = 1.f - fminf(amx, 1.f);
  float qy = 1.f - fminf(amy, 1.f);
  float r1 = wred_sum(re2.x*qx + re2.y*qy);
  float r2 = wred_sum(cex*qx + cey*qy);
  float r3 = wred_sum(re2.x + re2.y);
  float r4 = wred_sum(cex + cey);
  float r5 = wred_max(fmaxf(agx, agy));
  float r6 = wred_sum(mix + miy);
  if (lane==0){
    atomicAdd(&melN[n], r1);
    atomicAdd(&mcelN[n], r2);
    atomicAdd(&reS[n], r3);
    atomicAdd(&ceS[n], r4);
    atomicMax(&gmax[n], __float_as_uint(r5));
    atomicAdd(&miS[n], r6);
  }
  if (nz){
    float h = wred_sum(hsacc);
    if (lane==0) atomicAdd(hsG, h);
  }
}

// ---------------- finalization ----------------
__global__ __launch_bounds__(256) void k_final(const float* __restrict__ coords,
                                               const float* __restrict__ status,
                                               const float* __restrict__ miS,
                                               const float* __restrict__ melN,
                                               const float* __restrict__ mcelN,
                                               const float* __restrict__ reS,
                                               const float* __restrict__ ceS,
                                               const unsigned int* __restrict__ gmax,
                                               const float* __restrict__ hsG,
                                               float* __restrict__ out){
  __shared__ float wsum[4];
  int tid = threadIdx.x;
  int n = tid >> 2, q = tid & 3;   // n in 0..63, q selects 8 kp
  int s = n & 3;
  int np = (s==0) ? n+3 : n-1;
  float mc = 0.f, sl = 0.f;
  #pragma unroll
  for (int j=0;j<8;j++){
    int kp = q*8 + j;
    float dx = coords[(n*KPN+kp)*2+0] - coords[(np*KPN+kp)*2+0];
    float dy = coords[(n*KPN+kp)*2+1] - coords[(np*KPN+kp)*2+1];
    float st = status[n*KPN+kp];
    mc += sqrtf(dx*dx+dy*dy) * st * status[np*KPN+kp];
    sl += st;
  }
  mc += __shfl_xor(mc,1,64); mc += __shfl_xor(mc,2,64);
  sl += __shfl_xor(sl,1,64); sl += __shfl_xor(sl,2,64);
  float mint = 0.f;
  if (q==0){
    sl *= (1.f/KPN);
    float rsum = reS[n];
    float mel = melN[n]/(rsum+EPSF);
    float mcel = (s==0) ? 0.f : mcelN[n]/(ceS[n]+EPSF);
    // miS holds M = sum_px sum_kp min((1-ah)D, 0); full mi sum = 32*rsum + M
    // rc = (rsum - (32*rsum + M)/32)/hs = -M/(32*hs)
    float rc = (-miS[n]*(1.f/KPN)) / hsG[0];
    float itl = rc + 0.1f*mc;
    float ovl = fmaxf(__uint_as_float(gmax[n]) - 1.5f, 0.f)*(1.f/KPN);
    mint = 100.f*mel + 100.f*mcel + itl + 10.f*ovl + (1.f-mel)*2.5f*sl;
  }
  float r = wred_sum(mint);
  if ((tid&63)==0) wsum[tid>>6] = r;
  __syncthreads();
  if (tid==0) out[0] = (wsum[0]+wsum[1]+wsum[2]+wsum[3])*(1.f/64.f);
}

extern "C" void kernel_launch(void* const* d_in, const int* in_sizes, int n_in,
                              void* d_out, int out_size, void* d_ws, size_t ws_size,
                              hipStream_t stream){
  const float* coords = (const float*)d_in[0];
  const float* gauss  = (const float*)d_in[1];
  const float* status = (const float*)d_in[2];
  const float* images = (const float*)d_in[3];
  float* out = (float*)d_out;
  float* rimg = (float*)d_ws;                          // 1,769,472 f32
  float* ent  = rimg + (size_t)NIMG*CH*NPIX;           // 589,824 f32
  float* miS  = ent + (size_t)NIMG*NPIX;               // 64
  float* melN = miS + 64;
  float* mcelN = melN + 64;
  float* reS   = mcelN + 64;
  float* ceS   = reS + 64;
  unsigned int* gmax = (unsigned int*)(ceS + 64);      // 64
  float* hsG = (float*)(gmax + 64);                    // 1
  hipMemsetAsync(ent, 0, ((size_t)NIMG*NPIX + 6*64 + 1)*sizeof(float), stream);
  k_resize<<<(NIMG*CH*NPIX + 255)/256, 256, 0, stream>>>(images, rimg);
  k_entropy<<<dim3(9,64,3), 256, 0, stream>>>(rimg, ent);
  k_main<<<1152, 256, 0, stream>>>(gauss, status, ent, miS, melN, mcelN, reS, ceS, gmax, hsG);
  k_final<<<1,256,0,stream>>>(coords, status, miS, melN, mcelN, reS, ceS, gmax, hsG, out);
}